// Round 1
// baseline (732.521 us; speedup 1.0000x reference)
//
#include <hip/hip_runtime.h>
#include <math.h>

// Problem constants (DeepseekV2 MLA decode)
constexpr int kH    = 5120;
constexpr int kQLR  = 1536;
constexpr int kNH   = 128;
constexpr int kDQ   = 192;
constexpr int kDN   = 128;
constexpr int kDR   = 64;
constexpr int kKVLR = 512;
constexpr int kDV   = 128;

// ---------------------------------------------------------------------------
// Generic 2-batch GEMV: y[b,row] = sum_i W[row,i] * x[b,i], b in {0,1}
// One wave per row, 4 rows per 256-thread block. Coalesced float4 row reads.
// ---------------------------------------------------------------------------
template<int IN>
__global__ __launch_bounds__(256) void gemv2b_k(const float* __restrict__ W,
                                                const float* __restrict__ x,
                                                float* __restrict__ y, int R) {
  int lane = threadIdx.x & 63, wave = threadIdx.x >> 6;
  int row = blockIdx.x * 4 + wave;
  constexpr int F4 = IN / 256;  // float4 per lane
  const float4* W4 = (const float4*)(W + (size_t)row * IN);
  const float4* x0 = (const float4*)x;
  const float4* x1 = (const float4*)(x + IN);
  float a0 = 0.f, a1 = 0.f;
#pragma unroll 4
  for (int i = 0; i < F4; ++i) {
    int idx = lane + (i << 6);
    float4 w = W4[idx];
    float4 u = x0[idx];
    float4 v = x1[idx];
    a0 = fmaf(w.x, u.x, fmaf(w.y, u.y, fmaf(w.z, u.z, fmaf(w.w, u.w, a0))));
    a1 = fmaf(w.x, v.x, fmaf(w.y, v.y, fmaf(w.z, v.z, fmaf(w.w, v.w, a1))));
  }
#pragma unroll
  for (int off = 32; off > 0; off >>= 1) {
    a0 += __shfl_down(a0, off, 64);
    a1 += __shfl_down(a1, off, 64);
  }
  if (lane == 0) {
    y[row] = a0;
    y[(size_t)R + row] = a1;
  }
}

// ---------------------------------------------------------------------------
// RMSNorm over QLR=1536 per batch
// ---------------------------------------------------------------------------
__global__ __launch_bounds__(256) void rmsnorm_k(const float* __restrict__ qa,
                                                 const float* __restrict__ w,
                                                 float* __restrict__ out) {
  int b = blockIdx.x, t = threadIdx.x;
  const float* x = qa + (size_t)b * kQLR;
  float s = 0.f;
  for (int i = t; i < kQLR; i += 256) { float v = x[i]; s = fmaf(v, v, s); }
  __shared__ float red[4];
#pragma unroll
  for (int off = 32; off > 0; off >>= 1) s += __shfl_down(s, off, 64);
  if ((t & 63) == 0) red[t >> 6] = s;
  __syncthreads();
  float tot = red[0] + red[1] + red[2] + red[3];
  float scale = rsqrtf(tot / (float)kQLR + 1e-6f);
  for (int i = t; i < kQLR; i += 256) out[(size_t)b * kQLR + i] = x[i] * scale * w[i];
}

// ---------------------------------------------------------------------------
// RoPE on q_pe (in-place), position = kv_len-1. One thread per rotation pair.
// p enumerates [b][h][i], i<32.
// ---------------------------------------------------------------------------
__global__ __launch_bounds__(256) void rope_q_k(float* __restrict__ q, int pos) {
  int p = blockIdx.x * 256 + threadIdx.x;
  int i = p & 31;
  int h = (p >> 5) & (kNH - 1);
  int b = p >> 12;
  float inv = powf(10000.0f, -(float)i * (1.0f / 32.0f));
  float ang = (float)pos * inv;
  float s, c;
  sincosf(ang, &s, &c);
  float* base = q + ((size_t)b * kNH + h) * kDQ + kDN + 2 * i;
  float x0 = base[0], x1 = base[1];
  base[0] = x0 * c - x1 * s;
  base[1] = x0 * s + x1 * c;
}

// ---------------------------------------------------------------------------
// RoPE on k_pe cache -> rotated copy in ws. p enumerates [b][k][i].
// ---------------------------------------------------------------------------
__global__ __launch_bounds__(256) void rope_k_k(const float* __restrict__ kin,
                                                float* __restrict__ kout, int KV) {
  int p = blockIdx.x * 256 + threadIdx.x;
  int i = p & 31;
  int bk = p >> 5;
  int b = bk / KV;
  int k = bk - b * KV;
  float inv = powf(10000.0f, -(float)i * (1.0f / 32.0f));
  float ang = (float)k * inv;
  float s, c;
  sincosf(ang, &s, &c);
  const float* src = kin + ((size_t)b * KV + k) * kDR + 2 * i;
  float* dst = kout + ((size_t)b * KV + k) * kDR + 2 * i;
  float x0 = src[0], x1 = src[1];
  dst[0] = x0 * c - x1 * s;
  dst[1] = x0 * s + x1 * c;
}

// ---------------------------------------------------------------------------
// q absorption: qabs[b,h,c] = sum_d q_nope[b,h,d] * kv_b_w[h*256+d, c]
// grid (NH, 2 column-halves), 128 threads, both batches per block.
// ---------------------------------------------------------------------------
__global__ __launch_bounds__(128) void qabs_k(const float* __restrict__ q,
                                              const float* __restrict__ kvw,
                                              float* __restrict__ qabs) {
  int h = blockIdx.x, half = blockIdx.y;
  int t = threadIdx.x;  // 0..127
  __shared__ float qn[2 * kDN];
  qn[t]        = q[(size_t)h * kDQ + t];                 // b=0
  qn[128 + t]  = q[((size_t)kNH + h) * kDQ + t];         // b=1
  __syncthreads();
  int col = half * 256 + t * 2;
  float a0x = 0.f, a0y = 0.f, a1x = 0.f, a1y = 0.f;
  const float* wb = kvw + (size_t)h * 256 * kKVLR + col;
#pragma unroll 4
  for (int d = 0; d < kDN; ++d) {
    float2 w = *(const float2*)(wb + (size_t)d * kKVLR);
    float q0 = qn[d], q1 = qn[128 + d];
    a0x = fmaf(q0, w.x, a0x); a0y = fmaf(q0, w.y, a0y);
    a1x = fmaf(q1, w.x, a1x); a1y = fmaf(q1, w.y, a1y);
  }
  *(float2*)(qabs + (size_t)h * kKVLR + col)           = make_float2(a0x, a0y);
  *(float2*)(qabs + ((size_t)kNH + h) * kKVLR + col)   = make_float2(a1x, a1y);
}

// ---------------------------------------------------------------------------
// scores[b,h,k] = (qabs[b,h,:].c[b,k,:] + q_pe[b,h,:].kpe_rot[b,k,:]) / sqrt(192)
// grid (KV/64, 4 head-groups-of-32, B), block 256 (4 waves).
// Wave w handles heads hg*32 + w*8 .. +7; lane = k within the 64-k chunk.
// c chunk staged in LDS (stride 129 -> 2-way bank alias, free).
// q reads are wave-uniform (readfirstlane'd head base) -> scalar loads.
// ---------------------------------------------------------------------------
__global__ __launch_bounds__(256) void scores_k(const float* __restrict__ qabs,
                                                const float* __restrict__ qfull,
                                                const float* __restrict__ c,
                                                const float* __restrict__ kper,
                                                float* __restrict__ scores, int KV) {
  int kc = blockIdx.x, hg = blockIdx.y, b = blockIdx.z;
  int t = threadIdx.x, lane = t & 63, wave = t >> 6;
  int h0 = __builtin_amdgcn_readfirstlane(hg * 32 + wave * 8);
  int k0 = kc * 64;
  __shared__ float cl[64 * 129];
  __shared__ float kl[64 * 65];
  float acc[8];
#pragma unroll
  for (int j = 0; j < 8; ++j) acc[j] = 0.f;

  // stage rotated k_pe chunk [64][64]
  {
    const float4* src = (const float4*)(kper + ((size_t)b * KV + k0) * kDR);
#pragma unroll
    for (int i = 0; i < 4; ++i) {
      int idx = t + i * 256;
      int r = idx >> 4, c4 = idx & 15;
      float4 v = src[r * 16 + c4];
      float* d = &kl[r * 65 + (c4 << 2)];
      d[0] = v.x; d[1] = v.y; d[2] = v.z; d[3] = v.w;
    }
  }

  for (int cch = 0; cch < 4; ++cch) {
    __syncthreads();
    const float* cb = c + ((size_t)b * KV + k0) * kKVLR + cch * 128;
#pragma unroll
    for (int i = 0; i < 8; ++i) {
      int idx = t + i * 256;
      int r = idx >> 5, c4 = idx & 31;
      float4 v = *(const float4*)(cb + (size_t)r * kKVLR + (c4 << 2));
      float* d = &cl[r * 129 + (c4 << 2)];
      d[0] = v.x; d[1] = v.y; d[2] = v.z; d[3] = v.w;
    }
    __syncthreads();
    const float* qb = qabs + ((size_t)b * kNH + h0) * kKVLR + cch * 128;
#pragma unroll 4
    for (int cc = 0; cc < 128; ++cc) {
      float cv = cl[lane * 129 + cc];
#pragma unroll
      for (int j = 0; j < 8; ++j)
        acc[j] = fmaf(cv, qb[(size_t)j * kKVLR + cc], acc[j]);
    }
  }

  // rope (pe) contribution
  {
    const float* qp = qfull + ((size_t)b * kNH + h0) * kDQ + kDN;
#pragma unroll 4
    for (int i = 0; i < 64; ++i) {
      float kv = kl[lane * 65 + i];
#pragma unroll
      for (int j = 0; j < 8; ++j)
        acc[j] = fmaf(kv, qp[j * kDQ + i], acc[j]);
    }
  }

  const float scale = 1.0f / sqrtf(192.0f);
#pragma unroll
  for (int j = 0; j < 8; ++j)
    scores[((size_t)b * kNH + h0 + j) * KV + k0 + lane] = acc[j] * scale;
}

// ---------------------------------------------------------------------------
// softmax in-place over KV=2048 per (b,h). grid B*NH, block 256.
// ---------------------------------------------------------------------------
__global__ __launch_bounds__(256) void softmax_k(float* __restrict__ sc, int KV) {
  int t = threadIdx.x;
  float* row = sc + (size_t)blockIdx.x * KV;
  float vals[8];
  float m = -1e30f;
#pragma unroll
  for (int i = 0; i < 8; ++i) {
    vals[i] = row[t + i * 256];
    m = fmaxf(m, vals[i]);
  }
  __shared__ float red[4];
#pragma unroll
  for (int off = 32; off > 0; off >>= 1) m = fmaxf(m, __shfl_down(m, off, 64));
  if ((t & 63) == 0) red[t >> 6] = m;
  __syncthreads();
  m = fmaxf(fmaxf(red[0], red[1]), fmaxf(red[2], red[3]));
  __syncthreads();
  float s = 0.f;
#pragma unroll
  for (int i = 0; i < 8; ++i) {
    vals[i] = __expf(vals[i] - m);
    s += vals[i];
  }
#pragma unroll
  for (int off = 32; off > 0; off >>= 1) s += __shfl_down(s, off, 64);
  if ((t & 63) == 0) red[t >> 6] = s;
  __syncthreads();
  s = red[0] + red[1] + red[2] + red[3];
  float inv = 1.0f / s;
#pragma unroll
  for (int i = 0; i < 8; ++i) row[t + i * 256] = vals[i] * inv;
}

// ---------------------------------------------------------------------------
// ctx partials: ctxp[ks,b,h,c] = sum_{k in split ks} attn[b,h,k]*c[b,k,c]
// grid (16 k-splits, 8 head-groups-of-16, B), block 256 (thread -> float2 col)
// attn reads are block-uniform -> scalar loads.
// ---------------------------------------------------------------------------
__global__ __launch_bounds__(256) void ctx_partial_k(const float* __restrict__ attn,
                                                     const float* __restrict__ c,
                                                     float* __restrict__ ctxp, int KV) {
  int ks = blockIdx.x, hg = blockIdx.y, b = blockIdx.z;
  int t = threadIdx.x;
  int klen = KV >> 4;
  int k0 = ks * klen;
  float2 acc[16];
#pragma unroll
  for (int j = 0; j < 16; ++j) acc[j] = make_float2(0.f, 0.f);
  const float2* c2 = (const float2*)(c + (size_t)b * KV * kKVLR) + t;
  const float* arow = attn + ((size_t)b * kNH + hg * 16) * KV + k0;
  for (int k = 0; k < klen; ++k) {
    float2 cv = c2[(size_t)(k0 + k) * (kKVLR / 2)];
#pragma unroll
    for (int j = 0; j < 16; ++j) {
      float a = arow[(size_t)j * KV + k];
      acc[j].x = fmaf(a, cv.x, acc[j].x);
      acc[j].y = fmaf(a, cv.y, acc[j].y);
    }
  }
#pragma unroll
  for (int j = 0; j < 16; ++j) {
    float2* dst = (float2*)(ctxp + (((size_t)ks * 2 + b) * kNH + hg * 16 + j) * kKVLR);
    dst[t] = acc[j];
  }
}

// ---------------------------------------------------------------------------
// v-projection: oh[b,h,d] = sum_c W_v[h][d,c] * ctx[b,h,c]
// grid (NH, 2 d-halves), block 256. Phase 1 folds the 16 ctx partials.
// ---------------------------------------------------------------------------
__global__ __launch_bounds__(256) void vproj_k(const float* __restrict__ ctxp,
                                               const float* __restrict__ kvw,
                                               float* __restrict__ oh) {
  int h = blockIdx.x, half = blockIdx.y;
  int t = threadIdx.x, lane = t & 63, wave = t >> 6;
  __shared__ float cl[2 * kKVLR];
  {
    int b = t >> 7, c4 = t & 127;
    float4 s = make_float4(0.f, 0.f, 0.f, 0.f);
#pragma unroll
    for (int ks = 0; ks < 16; ++ks) {
      const float4* p = (const float4*)(ctxp + (((size_t)ks * 2 + b) * kNH + h) * kKVLR);
      float4 v = p[c4];
      s.x += v.x; s.y += v.y; s.z += v.z; s.w += v.w;
    }
    *(float4*)&cl[b * kKVLR + (c4 << 2)] = s;
  }
  __syncthreads();
  float cr0[8], cr1[8];
#pragma unroll
  for (int j = 0; j < 8; ++j) {
    cr0[j] = cl[lane * 8 + j];
    cr1[j] = cl[kKVLR + lane * 8 + j];
  }
  for (int i = 0; i < 16; ++i) {
    int d = half * 64 + wave * 16 + i;
    const float4* w4 = (const float4*)(kvw + ((size_t)h * 256 + 128 + d) * kKVLR + lane * 8);
    float4 wa = w4[0], wb = w4[1];
    float s0 = wa.x * cr0[0] + wa.y * cr0[1] + wa.z * cr0[2] + wa.w * cr0[3]
             + wb.x * cr0[4] + wb.y * cr0[5] + wb.z * cr0[6] + wb.w * cr0[7];
    float s1 = wa.x * cr1[0] + wa.y * cr1[1] + wa.z * cr1[2] + wa.w * cr1[3]
             + wb.x * cr1[4] + wb.y * cr1[5] + wb.z * cr1[6] + wb.w * cr1[7];
#pragma unroll
    for (int off = 32; off > 0; off >>= 1) {
      s0 += __shfl_down(s0, off, 64);
      s1 += __shfl_down(s1, off, 64);
    }
    if (lane == 0) {
      oh[(size_t)h * kDV + d] = s0;
      oh[((size_t)kNH + h) * kDV + d] = s1;
    }
  }
}

// ---------------------------------------------------------------------------
extern "C" void kernel_launch(void* const* d_in, const int* in_sizes, int n_in,
                              void* d_out, int out_size, void* d_ws, size_t ws_size,
                              hipStream_t stream) {
  const float* hs   = (const float*)d_in[0];
  const float* ckv  = (const float*)d_in[1];
  const float* kpe  = (const float*)d_in[2];
  const float* qaw  = (const float*)d_in[3];
  const float* qlnw = (const float*)d_in[4];
  const float* qbw  = (const float*)d_in[5];
  const float* kvbw = (const float*)d_in[6];
  const float* ow   = (const float*)d_in[7];
  float* out = (float*)d_out;

  int B  = in_sizes[0] / kH;              // 2
  int KV = in_sizes[2] / (B * kDR);       // 2048

  float* ws   = (float*)d_ws;
  float* qa   = ws;                                    // B*QLR
  float* qan  = qa + 4096;                             // B*QLR
  float* q    = qan + 4096;                            // B*NH*DQ
  float* qabs = q + (size_t)B * kNH * kDQ;             // B*NH*KVLR
  float* kper = qabs + (size_t)B * kNH * kKVLR;        // B*KV*DR
  float* sc   = kper + (size_t)B * KV * kDR;           // B*NH*KV
  float* ctxp = sc + (size_t)B * kNH * KV;             // 16*B*NH*KVLR
  float* oh   = ctxp + (size_t)16 * B * kNH * kKVLR;   // B*NH*DV

  // 1) q_a = hs @ q_a_w^T
  gemv2b_k<kH><<<kQLR / 4, 256, 0, stream>>>(qaw, hs, qa, kQLR);
  // 2) rmsnorm
  rmsnorm_k<<<B, 256, 0, stream>>>(qa, qlnw, qan);
  // 3) q = q_a_n @ q_b_w^T
  gemv2b_k<kQLR><<<(kNH * kDQ) / 4, 256, 0, stream>>>(qbw, qan, q, kNH * kDQ);
  // 4) rope q_pe (in place), pos = KV-1
  rope_q_k<<<(B * kNH * 32) / 256, 256, 0, stream>>>(q, KV - 1);
  // 5) rope k_pe -> kper
  rope_k_k<<<(B * KV * 32) / 256, 256, 0, stream>>>(kpe, kper, KV);
  // 6) q absorption
  qabs_k<<<dim3(kNH, 2), 128, 0, stream>>>(q, kvbw, qabs);
  // 7) scores
  scores_k<<<dim3(KV / 64, 4, B), 256, 0, stream>>>(qabs, q, ckv, kper, sc, KV);
  // 8) softmax
  softmax_k<<<B * kNH, 256, 0, stream>>>(sc, KV);
  // 9) ctx partials
  ctx_partial_k<<<dim3(16, 8, B), 256, 0, stream>>>(sc, ckv, ctxp, KV);
  // 10) v projection
  vproj_k<<<dim3(kNH, 2), 256, 0, stream>>>(ctxp, kvbw, oh);
  // 11) out = oh @ o_w^T
  gemv2b_k<kNH * kDV><<<kH / 4, 256, 0, stream>>>(ow, oh, out, kH);
}

// Round 2
// 668.074 us; speedup vs baseline: 1.0965x; 1.0965x over previous
//
#include <hip/hip_runtime.h>
#include <math.h>

// Problem constants (DeepseekV2 MLA decode)
constexpr int kH    = 5120;
constexpr int kQLR  = 1536;
constexpr int kNH   = 128;
constexpr int kDQ   = 192;
constexpr int kDN   = 128;
constexpr int kDR   = 64;
constexpr int kKVLR = 512;
constexpr int kDV   = 128;

// ---------------------------------------------------------------------------
// 2-batch GEMV, 2 rows per wave, split-K over blockIdx.y.
// y[b,row] = sum_i W[row,i]*x[b,i].  ATOMIC=true -> atomicAdd partials.
// grid (R/8, SPLIT), block 256.
// ---------------------------------------------------------------------------
template<int IN, int SPLIT, bool ATOMIC>
__global__ __launch_bounds__(256) void gemv2_k(const float* __restrict__ W,
                                               const float* __restrict__ x,
                                               float* __restrict__ y, int R) {
  constexpr int CH = IN / SPLIT;
  constexpr int F4 = CH / 256;  // float4 per lane per row-chunk
  int lane = threadIdx.x & 63, wave = threadIdx.x >> 6;
  int r0 = blockIdx.x * 8 + wave * 2;
  int c0 = blockIdx.y * CH;
  const float4* W0 = (const float4*)(W + (size_t)r0 * IN + c0);
  const float4* W1 = (const float4*)(W + (size_t)(r0 + 1) * IN + c0);
  const float4* x0 = (const float4*)(x + c0);
  const float4* x1 = (const float4*)(x + IN + c0);
  float a00 = 0.f, a01 = 0.f, a10 = 0.f, a11 = 0.f;
#pragma unroll 4
  for (int i = 0; i < F4; ++i) {
    int idx = lane + (i << 6);
    float4 w0 = W0[idx];
    float4 w1 = W1[idx];
    float4 u = x0[idx];
    float4 v = x1[idx];
    a00 = fmaf(w0.x,u.x,fmaf(w0.y,u.y,fmaf(w0.z,u.z,fmaf(w0.w,u.w,a00))));
    a01 = fmaf(w0.x,v.x,fmaf(w0.y,v.y,fmaf(w0.z,v.z,fmaf(w0.w,v.w,a01))));
    a10 = fmaf(w1.x,u.x,fmaf(w1.y,u.y,fmaf(w1.z,u.z,fmaf(w1.w,u.w,a10))));
    a11 = fmaf(w1.x,v.x,fmaf(w1.y,v.y,fmaf(w1.z,v.z,fmaf(w1.w,v.w,a11))));
  }
#pragma unroll
  for (int off = 32; off > 0; off >>= 1) {
    a00 += __shfl_down(a00, off, 64);
    a01 += __shfl_down(a01, off, 64);
    a10 += __shfl_down(a10, off, 64);
    a11 += __shfl_down(a11, off, 64);
  }
  if (lane == 0) {
    if (ATOMIC) {
      atomicAdd(&y[r0], a00);
      atomicAdd(&y[(size_t)R + r0], a01);
      atomicAdd(&y[r0 + 1], a10);
      atomicAdd(&y[(size_t)R + r0 + 1], a11);
    } else {
      y[r0] = a00;
      y[(size_t)R + r0] = a01;
      y[r0 + 1] = a10;
      y[(size_t)R + r0 + 1] = a11;
    }
  }
}

// ---------------------------------------------------------------------------
// RMSNorm over QLR=1536 per batch
// ---------------------------------------------------------------------------
__global__ __launch_bounds__(256) void rmsnorm_k(const float* __restrict__ qa,
                                                 const float* __restrict__ w,
                                                 float* __restrict__ out) {
  int b = blockIdx.x, t = threadIdx.x;
  const float* x = qa + (size_t)b * kQLR;
  float s = 0.f;
  for (int i = t; i < kQLR; i += 256) { float v = x[i]; s = fmaf(v, v, s); }
  __shared__ float red[4];
#pragma unroll
  for (int off = 32; off > 0; off >>= 1) s += __shfl_down(s, off, 64);
  if ((t & 63) == 0) red[t >> 6] = s;
  __syncthreads();
  float tot = red[0] + red[1] + red[2] + red[3];
  float scale = rsqrtf(tot / (float)kQLR + 1e-6f);
  for (int i = t; i < kQLR; i += 256) out[(size_t)b * kQLR + i] = x[i] * scale * w[i];
}

// ---------------------------------------------------------------------------
// RoPE on q_pe (in-place), position = kv_len-1.
// ---------------------------------------------------------------------------
__global__ __launch_bounds__(256) void rope_q_k(float* __restrict__ q, int pos) {
  int p = blockIdx.x * 256 + threadIdx.x;
  int i = p & 31;
  int h = (p >> 5) & (kNH - 1);
  int b = p >> 12;
  float inv = powf(10000.0f, -(float)i * (1.0f / 32.0f));
  float ang = (float)pos * inv;
  float s, c;
  sincosf(ang, &s, &c);
  float* base = q + ((size_t)b * kNH + h) * kDQ + kDN + 2 * i;
  float x0 = base[0], x1 = base[1];
  base[0] = x0 * c - x1 * s;
  base[1] = x0 * s + x1 * c;
}

// ---------------------------------------------------------------------------
// RoPE on k_pe cache -> rotated copy in ws.
// ---------------------------------------------------------------------------
__global__ __launch_bounds__(256) void rope_k_k(const float* __restrict__ kin,
                                                float* __restrict__ kout, int KV) {
  int p = blockIdx.x * 256 + threadIdx.x;
  int i = p & 31;
  int bk = p >> 5;
  int b = bk / KV;
  int k = bk - b * KV;
  float inv = powf(10000.0f, -(float)i * (1.0f / 32.0f));
  float ang = (float)k * inv;
  float s, c;
  sincosf(ang, &s, &c);
  const float* src = kin + ((size_t)b * KV + k) * kDR + 2 * i;
  float* dst = kout + ((size_t)b * KV + k) * kDR + 2 * i;
  float x0 = src[0], x1 = src[1];
  dst[0] = x0 * c - x1 * s;
  dst[1] = x0 * s + x1 * c;
}

// ---------------------------------------------------------------------------
// q absorption, d-split with atomics:
// qabs[b,h,c] += sum_{d in split} q_nope[b,h,d] * kv_b_w[h*256+d, c]
// grid (NH, 4), block 256 (thread -> float2 column).
// ---------------------------------------------------------------------------
__global__ __launch_bounds__(256) void qabs_k(const float* __restrict__ q,
                                              const float* __restrict__ kvw,
                                              float* __restrict__ qabs) {
  int h = blockIdx.x, ds = blockIdx.y;
  int t = threadIdx.x;
  __shared__ float qn[2][32];
  if (t < 64) {
    int b = t >> 5, d = t & 31;
    qn[b][d] = q[((size_t)b * kNH + h) * kDQ + ds * 32 + d];
  }
  __syncthreads();
  float a0x = 0.f, a0y = 0.f, a1x = 0.f, a1y = 0.f;
  const float* wb = kvw + ((size_t)h * 256 + ds * 32) * kKVLR + t * 2;
#pragma unroll 4
  for (int d = 0; d < 32; ++d) {
    float2 w = *(const float2*)(wb + (size_t)d * kKVLR);
    float q0 = qn[0][d], q1 = qn[1][d];
    a0x = fmaf(q0, w.x, a0x); a0y = fmaf(q0, w.y, a0y);
    a1x = fmaf(q1, w.x, a1x); a1y = fmaf(q1, w.y, a1y);
  }
  float* p0 = qabs + (size_t)h * kKVLR + t * 2;
  float* p1 = qabs + ((size_t)kNH + h) * kKVLR + t * 2;
  atomicAdd(p0, a0x); atomicAdd(p0 + 1, a0y);
  atomicAdd(p1, a1x); atomicAdd(p1 + 1, a1y);
}

// ---------------------------------------------------------------------------
// scores[b,h,k] = (qabs.c + q_pe.kpe_rot)/sqrt(192)
// grid (KV/64, 8 head-groups-of-16, B), block 256; wave handles 4 heads.
// c chunk in LDS (stride 129 -> 2-way alias, free); q via SGPR (uniform).
// ---------------------------------------------------------------------------
__global__ __launch_bounds__(256) void scores_k(const float* __restrict__ qabs,
                                                const float* __restrict__ qfull,
                                                const float* __restrict__ c,
                                                const float* __restrict__ kper,
                                                float* __restrict__ scores, int KV) {
  int kc = blockIdx.x, hg = blockIdx.y, b = blockIdx.z;
  int t = threadIdx.x, lane = t & 63, wave = t >> 6;
  int h0 = __builtin_amdgcn_readfirstlane(hg * 16 + wave * 4);
  int k0 = kc * 64;
  __shared__ float cl[64 * 129];
  __shared__ float kl[64 * 65];
  float acc[4] = {0.f, 0.f, 0.f, 0.f};

  // stage rotated k_pe chunk [64][64]
  {
    const float4* src = (const float4*)(kper + ((size_t)b * KV + k0) * kDR);
#pragma unroll
    for (int i = 0; i < 4; ++i) {
      int idx = t + i * 256;
      int r = idx >> 4, c4 = idx & 15;
      float4 v = src[r * 16 + c4];
      float* d = &kl[r * 65 + (c4 << 2)];
      d[0] = v.x; d[1] = v.y; d[2] = v.z; d[3] = v.w;
    }
  }

  for (int cch = 0; cch < 4; ++cch) {
    __syncthreads();
    const float* cb = c + ((size_t)b * KV + k0) * kKVLR + cch * 128;
#pragma unroll
    for (int i = 0; i < 8; ++i) {
      int idx = t + i * 256;
      int r = idx >> 5, c4 = idx & 31;
      float4 v = *(const float4*)(cb + (size_t)r * kKVLR + (c4 << 2));
      float* d = &cl[r * 129 + (c4 << 2)];
      d[0] = v.x; d[1] = v.y; d[2] = v.z; d[3] = v.w;
    }
    __syncthreads();
    const float* qb = qabs + ((size_t)b * kNH + h0) * kKVLR + cch * 128;
#pragma unroll 4
    for (int cc = 0; cc < 128; ++cc) {
      float cv = cl[lane * 129 + cc];
#pragma unroll
      for (int j = 0; j < 4; ++j)
        acc[j] = fmaf(cv, qb[(size_t)j * kKVLR + cc], acc[j]);
    }
  }

  // rope (pe) contribution
  {
    const float* qp = qfull + ((size_t)b * kNH + h0) * kDQ + kDN;
#pragma unroll 4
    for (int i = 0; i < 64; ++i) {
      float kv = kl[lane * 65 + i];
#pragma unroll
      for (int j = 0; j < 4; ++j)
        acc[j] = fmaf(kv, qp[j * kDQ + i], acc[j]);
    }
  }

  const float scale = 1.0f / sqrtf(192.0f);
#pragma unroll
  for (int j = 0; j < 4; ++j)
    scores[((size_t)b * kNH + h0 + j) * KV + k0 + lane] = acc[j] * scale;
}

// ---------------------------------------------------------------------------
// softmax in-place over KV=2048 per (b,h). grid B*NH, block 256.
// ---------------------------------------------------------------------------
__global__ __launch_bounds__(256) void softmax_k(float* __restrict__ sc, int KV) {
  int t = threadIdx.x;
  float* row = sc + (size_t)blockIdx.x * KV;
  float vals[8];
  float m = -1e30f;
#pragma unroll
  for (int i = 0; i < 8; ++i) {
    vals[i] = row[t + i * 256];
    m = fmaxf(m, vals[i]);
  }
  __shared__ float red[4];
#pragma unroll
  for (int off = 32; off > 0; off >>= 1) m = fmaxf(m, __shfl_down(m, off, 64));
  if ((t & 63) == 0) red[t >> 6] = m;
  __syncthreads();
  m = fmaxf(fmaxf(red[0], red[1]), fmaxf(red[2], red[3]));
  __syncthreads();
  float s = 0.f;
#pragma unroll
  for (int i = 0; i < 8; ++i) {
    vals[i] = __expf(vals[i] - m);
    s += vals[i];
  }
#pragma unroll
  for (int off = 32; off > 0; off >>= 1) s += __shfl_down(s, off, 64);
  if ((t & 63) == 0) red[t >> 6] = s;
  __syncthreads();
  s = red[0] + red[1] + red[2] + red[3];
  float inv = 1.0f / s;
#pragma unroll
  for (int i = 0; i < 8; ++i) row[t + i * 256] = vals[i] * inv;
}

// ---------------------------------------------------------------------------
// ctx partials: ctxp[ks,b,h,c] = sum_{k in 64-split ks} attn[b,h,k]*c[b,k,c]
// grid (32, 8 head-groups-of-16, B), block 256 (thread -> float2 col).
// attn transposed into LDS -> b128 broadcast reads (no s_load in hot loop).
// ---------------------------------------------------------------------------
__global__ __launch_bounds__(256) void ctx_partial_k(const float* __restrict__ attn,
                                                     const float* __restrict__ c,
                                                     float* __restrict__ ctxp, int KV) {
  int ks = blockIdx.x, hg = blockIdx.y, b = blockIdx.z;
  int t = threadIdx.x;
  int k0 = ks * 64, h0 = hg * 16;
  __shared__ float al[64 * 20];
#pragma unroll
  for (int i = 0; i < 4; ++i) {
    int idx = t + i * 256;
    int j = idx >> 6, k = idx & 63;
    al[k * 20 + j] = attn[((size_t)b * kNH + h0 + j) * KV + k0 + k];
  }
  __syncthreads();
  float2 acc[16];
#pragma unroll
  for (int j = 0; j < 16; ++j) acc[j] = make_float2(0.f, 0.f);
  const float2* c2 = (const float2*)(c + ((size_t)b * KV + k0) * kKVLR);
#pragma unroll 2
  for (int k = 0; k < 64; ++k) {
    float2 cv = c2[k * (kKVLR / 2) + t];
#pragma unroll
    for (int j4 = 0; j4 < 4; ++j4) {
      float4 av = *(const float4*)&al[k * 20 + j4 * 4];
      acc[j4*4+0].x = fmaf(av.x, cv.x, acc[j4*4+0].x);
      acc[j4*4+0].y = fmaf(av.x, cv.y, acc[j4*4+0].y);
      acc[j4*4+1].x = fmaf(av.y, cv.x, acc[j4*4+1].x);
      acc[j4*4+1].y = fmaf(av.y, cv.y, acc[j4*4+1].y);
      acc[j4*4+2].x = fmaf(av.z, cv.x, acc[j4*4+2].x);
      acc[j4*4+2].y = fmaf(av.z, cv.y, acc[j4*4+2].y);
      acc[j4*4+3].x = fmaf(av.w, cv.x, acc[j4*4+3].x);
      acc[j4*4+3].y = fmaf(av.w, cv.y, acc[j4*4+3].y);
    }
  }
#pragma unroll
  for (int j = 0; j < 16; ++j) {
    float2* dst = (float2*)(ctxp + (((size_t)ks * 2 + b) * kNH + h0 + j) * kKVLR);
    dst[t] = acc[j];
  }
}

// ---------------------------------------------------------------------------
// fold 32 ctx partials + v-projection: oh[b,h,d] = W_v[h][d,:] . ctx[b,h,:]
// grid (NH, 4 d-quarters), block 256.
// ---------------------------------------------------------------------------
__global__ __launch_bounds__(256) void vproj_k(const float* __restrict__ ctxp,
                                               const float* __restrict__ kvw,
                                               float* __restrict__ oh) {
  int h = blockIdx.x, dq = blockIdx.y;
  int t = threadIdx.x, lane = t & 63, wave = t >> 6;
  __shared__ float cf[2 * kKVLR];
  {
    int b = t >> 7, g = t & 127;
    float4 s = make_float4(0.f, 0.f, 0.f, 0.f);
#pragma unroll 8
    for (int ks = 0; ks < 32; ++ks) {
      const float4* p = (const float4*)(ctxp + (((size_t)ks * 2 + b) * kNH + h) * kKVLR);
      float4 v = p[g];
      s.x += v.x; s.y += v.y; s.z += v.z; s.w += v.w;
    }
    *(float4*)&cf[b * kKVLR + (g << 2)] = s;
  }
  __syncthreads();
  float cr0[8], cr1[8];
#pragma unroll
  for (int j = 0; j < 8; ++j) {
    cr0[j] = cf[lane * 8 + j];
    cr1[j] = cf[kKVLR + lane * 8 + j];
  }
#pragma unroll
  for (int i = 0; i < 8; ++i) {
    int d = dq * 32 + wave * 8 + i;
    const float4* w4 = (const float4*)(kvw + ((size_t)h * 256 + 128 + d) * kKVLR) + lane * 2;
    float4 wa = w4[0], wb = w4[1];
    float s0 = wa.x * cr0[0] + wa.y * cr0[1] + wa.z * cr0[2] + wa.w * cr0[3]
             + wb.x * cr0[4] + wb.y * cr0[5] + wb.z * cr0[6] + wb.w * cr0[7];
    float s1 = wa.x * cr1[0] + wa.y * cr1[1] + wa.z * cr1[2] + wa.w * cr1[3]
             + wb.x * cr1[4] + wb.y * cr1[5] + wb.z * cr1[6] + wb.w * cr1[7];
#pragma unroll
    for (int off = 32; off > 0; off >>= 1) {
      s0 += __shfl_down(s0, off, 64);
      s1 += __shfl_down(s1, off, 64);
    }
    if (lane == 0) {
      oh[(size_t)h * kDV + d] = s0;
      oh[((size_t)kNH + h) * kDV + d] = s1;
    }
  }
}

// ---------------------------------------------------------------------------
extern "C" void kernel_launch(void* const* d_in, const int* in_sizes, int n_in,
                              void* d_out, int out_size, void* d_ws, size_t ws_size,
                              hipStream_t stream) {
  const float* hs   = (const float*)d_in[0];
  const float* ckv  = (const float*)d_in[1];
  const float* kpe  = (const float*)d_in[2];
  const float* qaw  = (const float*)d_in[3];
  const float* qlnw = (const float*)d_in[4];
  const float* qbw  = (const float*)d_in[5];
  const float* kvbw = (const float*)d_in[6];
  const float* ow   = (const float*)d_in[7];
  float* out = (float*)d_out;

  int B  = in_sizes[0] / kH;              // 2
  int KV = in_sizes[2] / (B * kDR);       // 2048

  float* ws   = (float*)d_ws;
  float* qa   = ws;                                    // B*QLR
  float* qan  = qa + 4096;                             // B*QLR
  float* q    = qan + 4096;                            // B*NH*DQ
  float* qabs = q + (size_t)B * kNH * kDQ;             // B*NH*KVLR
  float* kper = qabs + (size_t)B * kNH * kKVLR;        // B*KV*DR
  float* sc   = kper + (size_t)B * KV * kDR;           // B*NH*KV
  float* ctxp = sc + (size_t)B * kNH * KV;             // 32*B*NH*KVLR
  float* oh   = ctxp + (size_t)32 * B * kNH * kKVLR;   // B*NH*DV

  // zero atomic-accumulation targets
  hipMemsetAsync(qa, 0, (size_t)B * kQLR * sizeof(float), stream);
  hipMemsetAsync(qabs, 0, (size_t)B * kNH * kKVLR * sizeof(float), stream);
  hipMemsetAsync(out, 0, (size_t)out_size * sizeof(float), stream);

  // 1) q_a = hs @ q_a_w^T  (split-4, atomic)
  gemv2_k<kH, 4, true><<<dim3(kQLR / 8, 4), 256, 0, stream>>>(qaw, hs, qa, kQLR);
  // 2) rmsnorm
  rmsnorm_k<<<B, 256, 0, stream>>>(qa, qlnw, qan);
  // 3) q = q_a_n @ q_b_w^T
  gemv2_k<kQLR, 1, false><<<dim3((kNH * kDQ) / 8, 1), 256, 0, stream>>>(qbw, qan, q, kNH * kDQ);
  // 4) rope q_pe (in place), pos = KV-1
  rope_q_k<<<(B * kNH * 32) / 256, 256, 0, stream>>>(q, KV - 1);
  // 5) rope k_pe -> kper
  rope_k_k<<<(B * KV * 32) / 256, 256, 0, stream>>>(kpe, kper, KV);
  // 6) q absorption (d-split, atomic)
  qabs_k<<<dim3(kNH, 4), 256, 0, stream>>>(q, kvbw, qabs);
  // 7) scores
  scores_k<<<dim3(KV / 64, 8, B), 256, 0, stream>>>(qabs, q, ckv, kper, sc, KV);
  // 8) softmax
  softmax_k<<<B * kNH, 256, 0, stream>>>(sc, KV);
  // 9) ctx partials
  ctx_partial_k<<<dim3(32, 8, B), 256, 0, stream>>>(sc, ckv, ctxp, KV);
  // 10) fold + v projection
  vproj_k<<<dim3(kNH, 4), 256, 0, stream>>>(ctxp, kvbw, oh);
  // 11) out = oh @ o_w^T  (split-4, atomic into d_out)
  gemv2_k<kNH * kDV, 4, true><<<dim3(kH / 8, 4), 256, 0, stream>>>(ow, oh, out, kH);
}